// Round 2
// baseline (12526.275 us; speedup 1.0000x reference)
//
#include <hip/hip_runtime.h>
#include <math.h>

// TemporalPredictionNetwork: L=4, S=512, H=1024, B=1.
// Round-7: dataflow synchronization (round-6 design) + hardened polls.
// Every cross-WG word is a packed 8B {f32 value, u32 round-tag} written with
// one relaxed agent-scope 64-bit store; consumers poll exactly the words they
// need (tag >= expected) instead of the old 64-WG atomic-counter barrier
// (which cost ~3.5 us of every 4.3 us phase).
// Poll hardening vs round-6: fast path is a single load (no overhead when the
// tag is already visible); the retry path backs off with s_sleep(1) (cuts
// fabric poll traffic while waiting) and is BOUNDED (~4M retries ~ 0.5 s) so
// any residual sync bug produces a wrong answer + counters instead of a hung
// container.
// WAR safety (audited): within a level, every phase polls the FULL shared
// vector (each thread its 2 entries), so passing phase k+1 certifies all WGs
// finished phase k's reads; cross-level reuse of the 4-deep hs/enc rings is
// guarded by cons[] back-pressure, whose publish (after P3's full erl poll)
// is ordered after all P2 enc-reads because each lane stores erl only after
// its enc read. dprec is 2-deep; P5's full enc poll certifies the slot's
// previous readers are done before it is rewritten at r+2.
#define NLVL 4
#define HDIM 1024
#define SEQ  512
#define THREADS 512
#define WGS_PER_LVL 64
#define NWG (NLVL * WGS_PER_LVL)
#define NWAVES (THREADS / 64)
#define SLICE_WAVES (WGS_PER_LVL * NWAVES)   // 512 waves per level

typedef unsigned short u16;
typedef unsigned int   u32;
typedef unsigned long long u64;

// ---- tagged workspace layout (u64 units) ----
// entry = {value f32 in [31:0], tag u32 in [63:32]}; round-r write -> tag r+1
#define TG_HS4   0                               // [4][NLVL][HDIM]
#define TG_ENC4  (TG_HS4  + 4*NLVL*HDIM)         // [4][NLVL][HDIM]
#define TG_T1    (TG_ENC4 + 4*NLVL*HDIM)         // [NLVL][HDIM]
#define TG_ERR   (TG_T1  + NLVL*HDIM)
#define TG_T2    (TG_ERR + NLVL*HDIM)
#define TG_DPREC (TG_T2  + NLVL*HDIM)            // [NLVL][8], slots (r&1), 64B stride
#define TG_CONS  (TG_DPREC + NLVL*8)             // [NLVL][8], cons u32 in low word
#define TG_FE    (TG_CONS + NLVL*8)              // [NLVL][8], fe partial f32 in low word
#define TG_FIN   (TG_FE + NLVL*8)                // finish counter
#define TG_END   (TG_FIN + 8)

// bf16 weight region (u16 units) at byte offset TG_END*8
#define BW_SQ   (NLVL * HDIM * HDIM)
#define BW_P1   0
#define BW_P2   (BW_P1 + BW_SQ)
#define BW_E1   (BW_P2 + BW_SQ)
#define BW_E2   (BW_E1 + BW_SQ)
#define BW_IH   (BW_E2 + BW_SQ)                  // L x 3H x H (gates i,g,o)
#define BW_IH_N (NLVL * 3 * HDIM * HDIM)
#define BW_TOTAL (BW_IH + BW_IH_N)

#define SPIN_CAP (1 << 22)                        // ~0.5 s worst case

__device__ __forceinline__ float gelu_f(float x) {
  return 0.5f * x * (1.0f + erff(x * 0.70710678118654752f));
}
__device__ __forceinline__ float sigmoid_f(float x) {
  return 1.0f / (1.0f + __expf(-x));
}

// relaxed agent-scope accesses
__device__ __forceinline__ float gload(const float* p) {
  return __hip_atomic_load((float*)p, __ATOMIC_RELAXED, __HIP_MEMORY_SCOPE_AGENT);
}
__device__ __forceinline__ void gstore(float* p, float v) {
  __hip_atomic_store(p, v, __ATOMIC_RELAXED, __HIP_MEMORY_SCOPE_AGENT);
}
__device__ __forceinline__ u32 uload(const u32* p) {
  return __hip_atomic_load((u32*)p, __ATOMIC_RELAXED, __HIP_MEMORY_SCOPE_AGENT);
}
__device__ __forceinline__ u64 tload(const u64* p) {
  return __hip_atomic_load((u64*)p, __ATOMIC_RELAXED, __HIP_MEMORY_SCOPE_AGENT);
}
__device__ __forceinline__ void tstore(u64* p, float v, u32 tag) {
  u64 x = ((u64)tag << 32) | (u64)__float_as_uint(v);
  __hip_atomic_store(p, x, __ATOMIC_RELAXED, __HIP_MEMORY_SCOPE_AGENT);
}
__device__ __forceinline__ float tval(u64 x) { return __uint_as_float((u32)x); }
__device__ __forceinline__ u32   ttag(u64 x) { return (u32)(x >> 32); }

// hardened tag poll: 1-load fast path; s_sleep backoff; bounded spin
__device__ __forceinline__ u64 pollt(const u64* p, u32 need) {
  u64 x = tload(p);
  if (ttag(x) >= need) return x;
  int spin = 0;
  for (;;) {
    x = tload(p);
    if (ttag(x) >= need) return x;
    if (++spin > 16) {
      __builtin_amdgcn_s_sleep(1);
      if (spin > SPIN_CAP) return x;     // give up -> wrong answer, not a hang
    }
  }
}

__device__ __forceinline__ float wredux(float v) {
#pragma unroll
  for (int off = 32; off > 0; off >>= 1) v += __shfl_down(v, off, 64);
  return v;
}

__device__ __forceinline__ float dot4f(float4 a, float4 x, float acc) {
  return fmaf(a.x, x.x, fmaf(a.y, x.y, fmaf(a.z, x.z, fmaf(a.w, x.w, acc))));
}
// bf16-pair helpers: element j in bits[15:0], j+1 in bits[31:16]
__device__ __forceinline__ float bflo(u32 u) { return __uint_as_float(u << 16); }
__device__ __forceinline__ float bfhi(u32 u) { return __uint_as_float(u & 0xffff0000u); }
__device__ __forceinline__ float bdot(uint2 u, float4 x, float acc) {
  acc = fmaf(bflo(u.x), x.x, acc); acc = fmaf(bfhi(u.x), x.y, acc);
  acc = fmaf(bflo(u.y), x.z, acc); acc = fmaf(bfhi(u.y), x.w, acc);
  return acc;
}
__device__ __forceinline__ u16 f2bf(float f) {   // RNE; weights are small normals
  u32 b = __float_as_uint(f);
  return (u16)((b + 0x7fffu + ((b >> 16) & 1u)) >> 16);
}

// matvec of rows r0,r1 against a 1024-vector, either tagged (st, poll tag>=need)
// or plain (sp). Weights prefetched BEFORE the polls so their latency hides
// under the wait. One __syncthreads (xb is a per-phase-parity LDS buffer).
template <bool BF16>
__device__ __forceinline__ void mv2(
    const float* __restrict__ Wf, const u16* __restrict__ Wb, int r0, int r1,
    const u64* __restrict__ st, const float* __restrict__ sp, u32 need,
    float* __restrict__ xb, int lane, float& o0, float& o1)
{
  float4 A0, A1, A2, A3, B0, B1, B2, B3;
  uint2  a0, a1, a2, a3, b0, b1, b2, b3;
  if constexpr (BF16) {
    const uint2* w0 = (const uint2*)(Wb + (size_t)r0 * HDIM);
    const uint2* w1 = (const uint2*)(Wb + (size_t)r1 * HDIM);
    a0 = w0[lane]; a1 = w0[lane + 64]; a2 = w0[lane + 128]; a3 = w0[lane + 192];
    b0 = w1[lane]; b1 = w1[lane + 64]; b2 = w1[lane + 128]; b3 = w1[lane + 192];
  } else {
    const float4* w0 = (const float4*)(Wf + (size_t)r0 * HDIM);
    const float4* w1 = (const float4*)(Wf + (size_t)r1 * HDIM);
    A0 = w0[lane]; A1 = w0[lane + 64]; A2 = w0[lane + 128]; A3 = w0[lane + 192];
    B0 = w1[lane]; B1 = w1[lane + 64]; B2 = w1[lane + 128]; B3 = w1[lane + 192];
  }
  const int i0 = threadIdx.x, i1 = threadIdx.x + THREADS;
  float v0, v1;
  if (st) {
    u64 A = pollt(st + i0, need);
    u64 B = pollt(st + i1, need);
    v0 = tval(A); v1 = tval(B);
  } else {
    v0 = sp[i0]; v1 = sp[i1];
  }
  xb[i0] = v0; xb[i1] = v1;
  __syncthreads();
  const float4* x4 = (const float4*)xb;
  float4 X0 = x4[lane], X1 = x4[lane + 64], X2 = x4[lane + 128], X3 = x4[lane + 192];
  float a, b;
  if constexpr (BF16) {
    a = bdot(a0, X0, 0.f); a = bdot(a1, X1, a); a = bdot(a2, X2, a); a = bdot(a3, X3, a);
    b = bdot(b0, X0, 0.f); b = bdot(b1, X1, b); b = bdot(b2, X2, b); b = bdot(b3, X3, b);
  } else {
    a = dot4f(A0, X0, 0.f); a = dot4f(A1, X1, a); a = dot4f(A2, X2, a); a = dot4f(A3, X3, a);
    b = dot4f(B0, X0, 0.f); b = dot4f(B1, X1, b); b = dot4f(B2, X2, b); b = dot4f(B3, X3, b);
  }
  o0 = wredux(a); o1 = wredux(b);
}

extern "C" __global__ void tpn_init(u64* tg) {
  int i = blockIdx.x * blockDim.x + threadIdx.x;
  int n = blockDim.x * gridDim.x;
  // hs: value 0, tag = lvl (lets P5@r=lvl read the zero initial state;
  // all later readers require larger tags so the init can't false-trigger)
  for (int k = i; k < 4 * NLVL * HDIM; k += n) {
    u32 lvl = (u32)((k / HDIM) % NLVL);
    tg[TG_HS4 + k] = ((u64)lvl) << 32;
  }
  for (int k = i; k < 4 * NLVL * HDIM; k += n) tg[TG_ENC4 + k] = 0ull;
  for (int k = i; k < 3 * NLVL * HDIM; k += n) tg[TG_T1 + k] = 0ull;   // T1,ERR,T2
  for (int k = i; k < (TG_END - TG_DPREC); k += n) tg[TG_DPREC + k] = 0ull;
}

// fp32 -> bf16 (RNE), contiguous
extern "C" __global__ void cvt_sq(const float* __restrict__ src,
                                  u16* __restrict__ dst, int n) {
  int i = blockIdx.x * blockDim.x + threadIdx.x;
  int stride = blockDim.x * gridDim.x;
  for (; i < n; i += stride) dst[i] = f2bf(src[i]);
}

// wih [L][4H][H] -> compact [L][3H][H] keeping gates {i=0, g=2, o=3}
extern "C" __global__ void cvt_ih(const float* __restrict__ wih,
                                  u16* __restrict__ dst) {
  int i = blockIdx.x * blockDim.x + threadIdx.x;
  int stride = blockDim.x * gridDim.x;
  const int per_lvl = 3 * HDIM * HDIM;
  for (; i < NLVL * per_lvl; i += stride) {
    int l = i / per_lvl;
    int rem = i - l * per_lvl;
    int gd = rem / (HDIM * HDIM);
    int rr = rem - gd * (HDIM * HDIM);
    int gs = (gd == 0) ? 0 : gd + 1;            // 0->i, 1->g, 2->o
    dst[i] = f2bf(wih[((size_t)(l * 4 + gs) * HDIM) * HDIM + rr]);
  }
}

template <bool BF16>
__global__ void __launch_bounds__(THREADS) tpn_main_t(
    const float* __restrict__ observed,
    const float* __restrict__ pw1, const float* __restrict__ pb1,
    const float* __restrict__ pw2, const float* __restrict__ pb2,
    const float* __restrict__ ew1, const float* __restrict__ eb1,
    const float* __restrict__ ew2, const float* __restrict__ eb2,
    const float* __restrict__ qw,  const float* __restrict__ qb,
    const float* __restrict__ wih, const float* __restrict__ bih,
    const float* __restrict__ bhh,
    float* __restrict__ out, u64* __restrict__ tg,
    const u16* __restrict__ bw)
{
  __shared__ __align__(16) float xl[2][HDIM];   // double-buffered x vector
  __shared__ float sred[NWAVES];
  const int wg   = blockIdx.x;
  const int lvl  = wg / WGS_PER_LVL;
  const int wgl  = wg % WGS_PER_LVL;
  const int wave = threadIdx.x >> 6;
  const int lane = threadIdx.x & 63;
  const int swid = wgl * NWAVES + wave;
  const int r0 = swid, r1 = swid + SLICE_WAVES;

  u64* hsT  = tg + TG_HS4;
  u64* encT = tg + TG_ENC4;
  u64* t1l  = tg + TG_T1  + (size_t)lvl * HDIM;
  u64* erl  = tg + TG_ERR + (size_t)lvl * HDIM;
  u64* t2l  = tg + TG_T2  + (size_t)lvl * HDIM;
  u64* dpl  = tg + TG_DPREC + (size_t)lvl * 8;
  u32* consl = (u32*)(tg + TG_CONS + (size_t)lvl * 8);        // own publish (lvl>0)
  u32* consd = (u32*)(tg + TG_CONS + (size_t)(lvl + 1) * 8);  // level above's

  // fp32 weight bases (fallback) and bf16 bases (primary)
  const float* Wp1 = pw1 + (size_t)lvl * HDIM * HDIM;
  const float* Wp2 = pw2 + (size_t)lvl * HDIM * HDIM;
  const float* We1 = ew1 + (size_t)lvl * HDIM * HDIM;
  const float* We2 = ew2 + (size_t)lvl * HDIM * HDIM;
  const float* Wih = wih + (size_t)lvl * 4 * HDIM * HDIM;
  const u16* Bp1 = bw + BW_P1 + (size_t)lvl * HDIM * HDIM;
  const u16* Bp2 = bw + BW_P2 + (size_t)lvl * HDIM * HDIM;
  const u16* Be1 = bw + BW_E1 + (size_t)lvl * HDIM * HDIM;
  const u16* Be2 = bw + BW_E2 + (size_t)lvl * HDIM * HDIM;
  const u16* Bih = bw + BW_IH + (size_t)lvl * 3 * HDIM * HDIM;
  const float* bp1 = pb1 + lvl * HDIM;
  const float* bp2 = pb2 + lvl * HDIM;
  const float* be1 = eb1 + lvl * HDIM;
  const float* be2 = eb2 + lvl * HDIM;
  const float* qwl = qw + lvl * HDIM;
  const float* bi  = bih + lvl * 4 * HDIM;
  const float* bh  = bhh + lvl * 4 * HDIM;

  unsigned ph = 0;          // LDS x parity, toggled per executed phase
  float fe_local = 0.f;

  for (int r = lvl; r < lvl + SEQ; ++r) {
    const int t = r - lvl;

    // ---- P1: t1 = gelu(pw1 @ h[lvl-1]@(r-1) + pb1)  (lvl>0) ----
    if (lvl > 0) {
      const u64* src = hsT + (size_t)(((r - 1) & 3) * NLVL + (lvl - 1)) * HDIM;
      float o0, o1;
      mv2<BF16>(Wp1, Bp1, r0, r1, src, nullptr, (u32)r, xl[ph & 1], lane, o0, o1);
      if (lane == 0) {
        tstore(t1l + r0, gelu_f(o0 + bp1[r0]), (u32)(r + 1));
        tstore(t1l + r1, gelu_f(o1 + bp1[r1]), (u32)(r + 1));
      }
      ph ^= 1;

      // ---- P2: pred = pw2 @ t1 + pb2 ; err = enc[lvl-1]@(r-1) - pred ----
      mv2<BF16>(Wp2, Bp2, r0, r1, t1l, nullptr, (u32)(r + 1), xl[ph & 1], lane, o0, o1);
      if (lane == 0) {
        const u64* eu = encT + (size_t)(((r - 1) & 3) * NLVL + (lvl - 1)) * HDIM;
        u64 A = pollt(eu + r0, (u32)r);
        u64 B = pollt(eu + r1, (u32)r);
        float p0 = o0 + bp2[r0], p1 = o1 + bp2[r1];
        tstore(erl + r0, tval(A) - p0, (u32)(r + 1));
        tstore(erl + r1, tval(B) - p1, (u32)(r + 1));
        if (t == SEQ - 1) { out[lvl * HDIM + r0] = p0; out[lvl * HDIM + r1] = p1; }
      }
      ph ^= 1;
    } else if (t == SEQ - 1) {
      for (int i = wgl * THREADS + threadIdx.x; i < HDIM; i += WGS_PER_LVL * THREADS)
        out[i] = 0.f;
    }

    // ---- P3: t2 = gelu(ew1 @ err + eb1) ; dprec = qw . err + qb ----
    {
      float4 Q0, Q1, Q2, Q3;
      const bool doq = (wgl == 0 && wave == 0);
      if (doq) {
        const float4* q4 = (const float4*)qwl;
        Q0 = q4[lane]; Q1 = q4[lane + 64]; Q2 = q4[lane + 128]; Q3 = q4[lane + 192];
      }
      const u64* st = (lvl == 0) ? nullptr : erl;
      const float* sp = observed + (size_t)t * HDIM;
      float o0, o1;
      mv2<BF16>(We1, Be1, r0, r1, st, sp, (u32)(r + 1), xl[ph & 1], lane, o0, o1);
      if (lane == 0) {
        tstore(t2l + r0, gelu_f(o0 + be1[r0]), (u32)(r + 1));
        tstore(t2l + r1, gelu_f(o1 + be1[r1]), (u32)(r + 1));
      }
      if (doq) {
        const float4* x4 = (const float4*)xl[ph & 1];
        float d = dot4f(Q0, x4[lane], 0.f);
        d = dot4f(Q1, x4[lane + 64], d);
        d = dot4f(Q2, x4[lane + 128], d);
        d = dot4f(Q3, x4[lane + 192], d);
        d = wredux(d);
        if (lane == 0) tstore(dpl + (r & 1), d + qb[lvl], (u32)(r + 1));
      }
      // back-pressure publish: err@r complete => whole level finished reading
      // enc[lvl-1]@(r-1) (P2) and hs[lvl-1]@(r-1) (P1).
      if (lvl > 0 && wgl == 0 && threadIdx.x == 0) {
        __hip_atomic_store(consl, (u32)(r + 1), __ATOMIC_RELAXED,
                           __HIP_MEMORY_SCOPE_AGENT);
      }
      ph ^= 1;
    }

    // ---- P4: enc = ew2 @ t2 + eb2  (round ring r&3) ----
    {
      // WAR guard before recycling enc/hs ring slots (3 rounds of slack;
      // normally satisfied on first load). Gates stores via mv2's barrier.
      if (lvl < NLVL - 1 && r >= lvl + 4 && threadIdx.x == 0) {
        u32 c = uload(consd);
        int spin = 0;
        while ((int)c < r - 2) {
          __builtin_amdgcn_s_sleep(1);
          if (++spin > SPIN_CAP) break;
          c = uload(consd);
        }
      }
      float o0, o1;
      mv2<BF16>(We2, Be2, r0, r1, t2l, nullptr, (u32)(r + 1), xl[ph & 1], lane, o0, o1);
      u64* dst = encT + (size_t)((r & 3) * NLVL + lvl) * HDIM;
      if (lane == 0) {
        float e0 = o0 + be2[r0], e1 = o1 + be2[r1];
        tstore(dst + r0, e0, (u32)(r + 1));
        tstore(dst + r1, e1, (u32)(r + 1));
        if (t == SEQ - 1) {
          out[NLVL * HDIM + lvl * HDIM + r0] = e0;
          out[NLVL * HDIM + lvl * HDIM + r1] = e1;
        }
      }
      ph ^= 1;
    }

    // ---- P5: LSTM on upd = hs + prec*enc ; f-gate dead (c0 = 0) ----
    {
      // prefetch 6 gate rows (i,g,o) x (r0,r1) before the polls
      float4 Wf[6][4];
      uint2  Wb[6][4];
      if constexpr (BF16) {
        const u16* Rr[6] = {
          Bih + (size_t)r0 * HDIM, Bih + (size_t)(HDIM + r0) * HDIM,
          Bih + (size_t)(2 * HDIM + r0) * HDIM,
          Bih + (size_t)r1 * HDIM, Bih + (size_t)(HDIM + r1) * HDIM,
          Bih + (size_t)(2 * HDIM + r1) * HDIM };
#pragma unroll
        for (int k = 0; k < 6; ++k) {
          const uint2* w = (const uint2*)Rr[k];
          Wb[k][0] = w[lane]; Wb[k][1] = w[lane + 64];
          Wb[k][2] = w[lane + 128]; Wb[k][3] = w[lane + 192];
        }
      } else {
        const float* Rr[6] = {
          Wih + (size_t)r0 * HDIM, Wih + (size_t)(2 * HDIM + r0) * HDIM,
          Wih + (size_t)(3 * HDIM + r0) * HDIM,
          Wih + (size_t)r1 * HDIM, Wih + (size_t)(2 * HDIM + r1) * HDIM,
          Wih + (size_t)(3 * HDIM + r1) * HDIM };
#pragma unroll
        for (int k = 0; k < 6; ++k) {
          const float4* w = (const float4*)Rr[k];
          Wf[k][0] = w[lane]; Wf[k][1] = w[lane + 64];
          Wf[k][2] = w[lane + 128]; Wf[k][3] = w[lane + 192];
        }
      }
      const u64* el   = encT + (size_t)((r & 3) * NLVL + lvl) * HDIM;
      const u64* hold = hsT + (size_t)(((r - 1) & 3) * NLVL + lvl) * HDIM;
      const int i0 = threadIdx.x, i1 = threadIdx.x + THREADS;
      u64 E0 = pollt(el + i0, (u32)(r + 1));
      u64 E1 = pollt(el + i1, (u32)(r + 1));
      u64 H0 = pollt(hold + i0, (u32)r);
      u64 H1 = pollt(hold + i1, (u32)r);
      u64 D  = pollt(dpl + (r & 1), (u32)(r + 1));
      float e0 = tval(E0), e1 = tval(E1), h0 = tval(H0), h1 = tval(H1);
      float pr = sigmoid_f(tval(D));
      float* xb = xl[ph & 1];
      xb[i0] = fmaf(pr, e0, h0);
      xb[i1] = fmaf(pr, e1, h1);
      __syncthreads();
      const float4* x4 = (const float4*)xb;
      float4 X[4] = { x4[lane], x4[lane + 64], x4[lane + 128], x4[lane + 192] };
      float d[6];
#pragma unroll
      for (int k = 0; k < 6; ++k) {
        float a;
        if constexpr (BF16) {
          a = bdot(Wb[k][0], X[0], 0.f);
          a = bdot(Wb[k][1], X[1], a);
          a = bdot(Wb[k][2], X[2], a);
          a = bdot(Wb[k][3], X[3], a);
        } else {
          a = dot4f(Wf[k][0], X[0], 0.f);
          a = dot4f(Wf[k][1], X[1], a);
          a = dot4f(Wf[k][2], X[2], a);
          a = dot4f(Wf[k][3], X[3], a);
        }
        d[k] = wredux(a);
      }
      u64* hnew = hsT + (size_t)((r & 3) * NLVL + lvl) * HDIM;
      if (lane == 0) {
        float gi0 = sigmoid_f(d[0] + bi[r0] + bh[r0]);
        float gg0 = tanhf(d[1] + bi[2 * HDIM + r0] + bh[2 * HDIM + r0]);
        float go0 = sigmoid_f(d[2] + bi[3 * HDIM + r0] + bh[3 * HDIM + r0]);
        tstore(hnew + r0, go0 * tanhf(gi0 * gg0), (u32)(r + 1));
        float gi1 = sigmoid_f(d[3] + bi[r1] + bh[r1]);
        float gg1 = tanhf(d[4] + bi[2 * HDIM + r1] + bh[2 * HDIM + r1]);
        float go1 = sigmoid_f(d[5] + bi[3 * HDIM + r1] + bh[3 * HDIM + r1]);
        tstore(hnew + r1, go1 * tanhf(gi1 * gg1), (u32)(r + 1));
      }
      if (wgl == 0) {   // fe += prec * sum(enc^2)
        float s = fmaf(e0, e0, e1 * e1);
        s = wredux(s);
        if (lane == 0) sred[wave] = s;
        __syncthreads();
        if (threadIdx.x == 0) {
          float tot = 0.f;
#pragma unroll
          for (int k = 0; k < NWAVES; ++k) tot += sred[k];
          fe_local += pr * tot;
        }
      }
      ph ^= 1;
    }
  }

  float* fel = (float*)(tg + TG_FE + (size_t)lvl * 8);
  u32* fin = (u32*)(tg + TG_FIN);
  if (wgl == 0 && threadIdx.x == 0) {
    gstore(fel, fe_local);
    asm volatile("s_waitcnt vmcnt(0)" ::: "memory");
    __hip_atomic_fetch_add(fin, 1u, __ATOMIC_RELAXED, __HIP_MEMORY_SCOPE_AGENT);
  }
  if (wg == 0 && threadIdx.x == 0) {
    int spin = 0;
    while (uload(fin) < (u32)NLVL) {
      __builtin_amdgcn_s_sleep(1);
      if (++spin > SPIN_CAP) break;
    }
    float s = 0.f;
    for (int k = 0; k < NLVL; ++k) s += gload((float*)(tg + TG_FE + (size_t)k * 8));
    out[2 * NLVL * HDIM] = s;
  }
}

extern "C" void kernel_launch(void* const* d_in, const int* in_sizes, int n_in,
                              void* d_out, int out_size, void* d_ws, size_t ws_size,
                              hipStream_t stream) {
  const float* observed = (const float*)d_in[0];
  const float* pw1 = (const float*)d_in[1];
  const float* pb1 = (const float*)d_in[2];
  const float* pw2 = (const float*)d_in[3];
  const float* pb2 = (const float*)d_in[4];
  const float* ew1 = (const float*)d_in[5];
  const float* eb1 = (const float*)d_in[6];
  const float* ew2 = (const float*)d_in[7];
  const float* eb2 = (const float*)d_in[8];
  const float* qw  = (const float*)d_in[9];
  const float* qb  = (const float*)d_in[10];
  const float* wih = (const float*)d_in[11];
  // d_in[12] = whh — unused (h0 == 0 per step)
  const float* bih = (const float*)d_in[13];
  const float* bhh = (const float*)d_in[14];
  float* out = (float*)d_out;
  u64* tg = (u64*)d_ws;
  u16* bw = (u16*)((char*)d_ws + (size_t)TG_END * 8);

  const size_t need = (size_t)TG_END * 8 + (size_t)BW_TOTAL * 2;
  const bool use_bf16 = (ws_size >= need);   // ws_size fixed -> same path every call

  hipLaunchKernelGGL(tpn_init, dim3(64), dim3(256), 0, stream, tg);

  if (use_bf16) {
    const int nsq = NLVL * HDIM * HDIM;
    hipLaunchKernelGGL(cvt_sq, dim3(512), dim3(256), 0, stream, pw1, bw + BW_P1, nsq);
    hipLaunchKernelGGL(cvt_sq, dim3(512), dim3(256), 0, stream, pw2, bw + BW_P2, nsq);
    hipLaunchKernelGGL(cvt_sq, dim3(512), dim3(256), 0, stream, ew1, bw + BW_E1, nsq);
    hipLaunchKernelGGL(cvt_sq, dim3(512), dim3(256), 0, stream, ew2, bw + BW_E2, nsq);
    hipLaunchKernelGGL(cvt_ih, dim3(512), dim3(256), 0, stream, wih, bw + BW_IH);
  }

  const u16* bwc = bw;
  void* args[] = { &observed, &pw1, &pb1, &pw2, &pb2, &ew1, &eb1, &ew2, &eb2,
                   &qw, &qb, &wih, &bih, &bhh, &out, &tg, &bwc };
  if (use_bf16) {
    (void)hipLaunchCooperativeKernel((void*)tpn_main_t<true>, dim3(NWG),
                                     dim3(THREADS), args, 0, stream);
  } else {
    (void)hipLaunchCooperativeKernel((void*)tpn_main_t<false>, dim3(NWG),
                                     dim3(THREADS), args, 0, stream);
  }
}

// Round 3
// 7137.231 us; speedup vs baseline: 1.7551x; 1.7551x over previous
//
#include <hip/hip_runtime.h>
#include <math.h>

// TemporalPredictionNetwork: L=4, S=512, H=1024, B=1.
// Round-8: STAGE-PARALLEL dataflow. Round-7 measurement: phase time stuck at
// ~4.8 us whether sync is barriers or tags -> the floor is 5 SERIAL cross-WG
// hops per round (each phase is a level-wide all-to-all). But the only
// loop-carried dependence per level is h@r -> h@(r+1); P1..P4 are a
// feed-forward pipeline across rounds. So: give each phase its own WG group
// with its own round counter. Steady-state initiation interval = 1 hop
// (h store -> poll) + LSTM compute, not 5 hops.
// Enabler: weights live in VGPRs (bf16, 16 rows x 8 regs per wave, loaded
// once) -> no per-round weight streaming -> groups can be small:
//   square matvec groups (P1,P2,P3,P4): 8 WGs x 8 waves, 16 rows/wave
//   LSTM group (P5): 32 WGs x 8 waves, 4 h-rows (12 gate rows)/wave
// 240 WGs total, 1 per CU. Tagged 8B {f32,round} words as in round-7;
// depth-4 rings for t1/err/t2/enc/h/dprec; WAR guarded by per-WG progress
// words (prog = "my round-r input reads are done", published at the
// post-fill barrier). Guards reference strictly earlier rounds -> acyclic
// -> deadlock-free. All polls bounded (wrong answer, never a hang).
#define NLVL 4
#define HDIM 1024
#define SEQ  512
#define THREADS 512
#define NWAVES (THREADS / 64)
#define GP 8                 // WGs per square-phase group
#define GL 32                // WGs per LSTM group
#define NWG (48 + 3 * 64)    // lvl0: 8+8+32; lvl1-3: 8+8+8+8+32

typedef unsigned short u16;
typedef unsigned int   u32;
typedef unsigned long long u64;

// ---- tagged workspace layout (u64 units) ----
// entry = {value f32 in [31:0], tag u32 in [63:32]}; round-r write -> tag r+1
#define TG_HS4   0                       // [4][NLVL][HDIM]
#define TG_ENC4  16384                   // [4][NLVL][HDIM]
#define TG_T1R   32768                   // [NLVL][4][HDIM]
#define TG_ERRR  49152                   // [NLVL][4][HDIM]
#define TG_T2R   65536                   // [NLVL][4][HDIM]
#define TG_DPR   81920                   // [NLVL][4] slots, 8-u64 stride
#define TG_PROG  82048                   // [20 groups][32 wgs], 8-u64 stride
#define TG_FE    87168                   // [NLVL][8]
#define TG_FIN   87200
#define TG_END   87208

// bf16 weight region (u16 units) at byte offset TG_END*8
#define BW_SQ   (NLVL * HDIM * HDIM)
#define BW_P1   0
#define BW_P2   (BW_P1 + BW_SQ)
#define BW_E1   (BW_P2 + BW_SQ)
#define BW_E2   (BW_E1 + BW_SQ)
#define BW_IH   (BW_E2 + BW_SQ)          // L x 3H x H (gates i,g,o)
#define BW_IH_N (NLVL * 3 * HDIM * HDIM)
#define BW_TOTAL (BW_IH + BW_IH_N)

#define SPIN_CAP (1 << 22)

__device__ __forceinline__ float gelu_f(float x) {
  return 0.5f * x * (1.0f + erff(x * 0.70710678118654752f));
}
__device__ __forceinline__ float sigmoid_f(float x) {
  return 1.0f / (1.0f + __expf(-x));
}

__device__ __forceinline__ float gload(const float* p) {
  return __hip_atomic_load((float*)p, __ATOMIC_RELAXED, __HIP_MEMORY_SCOPE_AGENT);
}
__device__ __forceinline__ void gstore(float* p, float v) {
  __hip_atomic_store(p, v, __ATOMIC_RELAXED, __HIP_MEMORY_SCOPE_AGENT);
}
__device__ __forceinline__ u32 uload(const u32* p) {
  return __hip_atomic_load((u32*)p, __ATOMIC_RELAXED, __HIP_MEMORY_SCOPE_AGENT);
}
__device__ __forceinline__ u64 tload(const u64* p) {
  return __hip_atomic_load((u64*)p, __ATOMIC_RELAXED, __HIP_MEMORY_SCOPE_AGENT);
}
__device__ __forceinline__ void tstore(u64* p, float v, u32 tag) {
  u64 x = ((u64)tag << 32) | (u64)__float_as_uint(v);
  __hip_atomic_store(p, x, __ATOMIC_RELAXED, __HIP_MEMORY_SCOPE_AGENT);
}
__device__ __forceinline__ float tval(u64 x) { return __uint_as_float((u32)x); }
__device__ __forceinline__ u32   ttag(u64 x) { return (u32)(x >> 32); }

// hardened tag poll: 1-load fast path; s_sleep backoff; bounded spin
__device__ __forceinline__ u64 pollt(const u64* p, u32 need) {
  u64 x = tload(p);
  if (ttag(x) >= need) return x;
  int spin = 0;
  for (;;) {
    x = tload(p);
    if (ttag(x) >= need) return x;
    if (++spin > 16) {
      __builtin_amdgcn_s_sleep(1);
      if (spin > SPIN_CAP) return x;
    }
  }
}

// batched min-scan guard over a consumer group's progress words
template <int N>
__device__ __forceinline__ void gscan(const u64* pb, u32 need) {
  int spin = 0;
  for (;;) {
    u32 mn = 0xffffffffu;
#pragma unroll
    for (int w = 0; w < N; ++w) {
      u32 c = uload((const u32*)(pb + (size_t)w * 8));
      mn = (c < mn) ? c : mn;
    }
    if (mn >= need) return;
    __builtin_amdgcn_s_sleep(2);
    if (++spin > (SPIN_CAP >> 6)) return;
  }
}

__device__ __forceinline__ float wredux_all(float v) {   // butterfly: all lanes get sum
#pragma unroll
  for (int off = 32; off; off >>= 1) v += __shfl_xor(v, off, 64);
  return v;
}

__device__ __forceinline__ float dot4f(float4 a, float4 x, float acc) {
  return fmaf(a.x, x.x, fmaf(a.y, x.y, fmaf(a.z, x.z, fmaf(a.w, x.w, acc))));
}
__device__ __forceinline__ float bflo(u32 u) { return __uint_as_float(u << 16); }
__device__ __forceinline__ float bfhi(u32 u) { return __uint_as_float(u & 0xffff0000u); }
__device__ __forceinline__ float bdot(uint2 u, float4 x, float acc) {
  acc = fmaf(bflo(u.x), x.x, acc); acc = fmaf(bfhi(u.x), x.y, acc);
  acc = fmaf(bflo(u.y), x.z, acc); acc = fmaf(bfhi(u.y), x.w, acc);
  return acc;
}
__device__ __forceinline__ u16 f2bf(float f) {
  u32 b = __float_as_uint(f);
  return (u16)((b + 0x7fffu + ((b >> 16) & 1u)) >> 16);
}

// fill LDS x-vector from tagged (st) or plain (sp) 1024-vector
__device__ __forceinline__ void fill_x(const u64* st, const float* sp, u32 need,
                                       float* xb) {
  const int i0 = threadIdx.x, i1 = threadIdx.x + THREADS;
  float v0, v1;
  if (st) { v0 = tval(pollt(st + i0, need)); v1 = tval(pollt(st + i1, need)); }
  else    { v0 = sp[i0]; v1 = sp[i1]; }
  xb[i0] = v0; xb[i1] = v1;
}

template <bool BF16>
__device__ __forceinline__ void loadW16(uint2 (&Wr)[16][4], const u16* Wb,
                                        int base, int lane) {
  if constexpr (BF16) {
#pragma unroll
    for (int k = 0; k < 16; ++k) {
      const uint2* w = (const uint2*)(Wb + (size_t)(base + k) * HDIM);
      Wr[k][0] = w[lane]; Wr[k][1] = w[lane + 64];
      Wr[k][2] = w[lane + 128]; Wr[k][3] = w[lane + 192];
    }
  }
}

// 16-row matvec; returns o_j in lane j (j<16)
template <bool BF16>
__device__ __forceinline__ float dot16_keep(const uint2 (&Wr)[16][4],
                                            const float* Wf, int base,
                                            const float4* x4, int lane) {
  float4 X0 = x4[lane], X1 = x4[lane + 64], X2 = x4[lane + 128], X3 = x4[lane + 192];
  float keep = 0.f;
#pragma unroll
  for (int k = 0; k < 16; ++k) {
    float a;
    if constexpr (BF16) {
      a = bdot(Wr[k][0], X0, 0.f); a = bdot(Wr[k][1], X1, a);
      a = bdot(Wr[k][2], X2, a);  a = bdot(Wr[k][3], X3, a);
    } else {
      const float4* w = (const float4*)(Wf + (size_t)(base + k) * HDIM);
      float4 A0 = w[lane], A1 = w[lane + 64], A2 = w[lane + 128], A3 = w[lane + 192];
      a = dot4f(A0, X0, 0.f); a = dot4f(A1, X1, a);
      a = dot4f(A2, X2, a);   a = dot4f(A3, X3, a);
    }
    a = wredux_all(a);
    keep = (lane == k) ? a : keep;
  }
  return keep;
}

extern "C" __global__ void tpn_init(u64* tg) {
  int i = blockIdx.x * blockDim.x + threadIdx.x;
  int n = blockDim.x * gridDim.x;
  // hs: value 0, tag = lvl (satisfies P5@r=lvl reading zero initial state)
  for (int k = i; k < 4 * NLVL * HDIM; k += n) {
    u32 lvl = (u32)((k / HDIM) % NLVL);
    tg[TG_HS4 + k] = ((u64)lvl) << 32;
  }
  for (int k = i; k < 4 * NLVL * HDIM; k += n) tg[TG_ENC4 + k] = 0ull;
  for (int k = i; k < 3 * NLVL * 4 * HDIM; k += n) tg[TG_T1R + k] = 0ull; // t1,err,t2
  for (int k = i; k < (TG_END - TG_DPR); k += n) tg[TG_DPR + k] = 0ull;
}

extern "C" __global__ void cvt_sq(const float* __restrict__ src,
                                  u16* __restrict__ dst, int n) {
  int i = blockIdx.x * blockDim.x + threadIdx.x;
  int stride = blockDim.x * gridDim.x;
  for (; i < n; i += stride) dst[i] = f2bf(src[i]);
}

// wih [L][4H][H] -> compact [L][3H][H] keeping gates {i=0, g=2, o=3}
extern "C" __global__ void cvt_ih(const float* __restrict__ wih,
                                  u16* __restrict__ dst) {
  int i = blockIdx.x * blockDim.x + threadIdx.x;
  int stride = blockDim.x * gridDim.x;
  const int per_lvl = 3 * HDIM * HDIM;
  for (; i < NLVL * per_lvl; i += stride) {
    int l = i / per_lvl;
    int rem = i - l * per_lvl;
    int gd = rem / (HDIM * HDIM);
    int rr = rem - gd * (HDIM * HDIM);
    int gs = (gd == 0) ? 0 : gd + 1;
    dst[i] = f2bf(wih[((size_t)(l * 4 + gs) * HDIM) * HDIM + rr]);
  }
}

__device__ __forceinline__ u64* progp(u64* tg, int l, int ph) {
  return tg + TG_PROG + ((size_t)(l * 5 + ph) * 32) * 8;
}
__device__ __forceinline__ void pub(u64* w, u32 v) {
  __hip_atomic_store((u32*)w, v, __ATOMIC_RELAXED, __HIP_MEMORY_SCOPE_AGENT);
}

template <bool BF16>
__global__ void __launch_bounds__(THREADS) tpn_main_t(
    const float* __restrict__ observed,
    const float* __restrict__ pw1, const float* __restrict__ pb1,
    const float* __restrict__ pw2, const float* __restrict__ pb2,
    const float* __restrict__ ew1, const float* __restrict__ eb1,
    const float* __restrict__ ew2, const float* __restrict__ eb2,
    const float* __restrict__ qw,  const float* __restrict__ qb,
    const float* __restrict__ wih, const float* __restrict__ bih,
    const float* __restrict__ bhh,
    float* __restrict__ out, u64* __restrict__ tg,
    const u16* __restrict__ bw)
{
  __shared__ __align__(16) float xl[2][HDIM];
  __shared__ float sred[NWAVES];
  const int bx = blockIdx.x;
  int lvl, phase, wgl;
  if (bx < 48) {
    lvl = 0;
    if (bx < 8)       { phase = 2; wgl = bx; }
    else if (bx < 16) { phase = 3; wgl = bx - 8; }
    else              { phase = 4; wgl = bx - 16; }
  } else {
    int b = bx - 48; lvl = 1 + b / 64; int o = b % 64;
    if (o < 8)       { phase = 0; wgl = o; }
    else if (o < 16) { phase = 1; wgl = o - 8; }
    else if (o < 24) { phase = 2; wgl = o - 16; }
    else if (o < 32) { phase = 3; wgl = o - 24; }
    else             { phase = 4; wgl = o - 32; }
  }
  const int wave = threadIdx.x >> 6, lane = threadIdx.x & 63;

  u64* hsT  = tg + TG_HS4;
  u64* encT = tg + TG_ENC4;
  u64* myprog = progp(tg, lvl, phase) + (size_t)wgl * 8;

  if (phase == 4) {
    // ================= P5: LSTM h-chain =================
    const int wid = wgl * NWAVES + wave;        // 0..255
    const int b4 = wid * 4;                     // 4 h-rows per wave
    const u16* Bih = bw + BW_IH + (size_t)lvl * 3 * HDIM * HDIM;
    const float* Wih = wih + (size_t)lvl * 4 * HDIM * HDIM;
    const float* bi = bih + lvl * 4 * HDIM;
    const float* bh = bhh + lvl * 4 * HDIM;
    uint2 Wr[12][4];
    if constexpr (BF16) {
#pragma unroll
      for (int k = 0; k < 12; ++k) {
        const int hr = k / 3, g = k % 3;
        const uint2* w = (const uint2*)(Bih + ((size_t)g * HDIM + b4 + hr) * HDIM);
        Wr[k][0] = w[lane]; Wr[k][1] = w[lane + 64];
        Wr[k][2] = w[lane + 128]; Wr[k][3] = w[lane + 192];
      }
    }
    float mb0 = 0.f, mb1 = 0.f, mb2 = 0.f;
    if (lane < 4) {
      const int rr = b4 + lane;
      mb0 = bi[rr] + bh[rr];
      mb1 = bi[2 * HDIM + rr] + bh[2 * HDIM + rr];
      mb2 = bi[3 * HDIM + rr] + bh[3 * HDIM + rr];
    }
    float fe_local = 0.f;
    for (int r = lvl; r < lvl + SEQ; ++r) {
      float* xb = xl[r & 1];
      const int i0 = threadIdx.x, i1 = threadIdx.x + THREADS;
      const u64* el = encT + (size_t)((r & 3) * NLVL + lvl) * HDIM;
      const u64* hold = hsT + (size_t)(((r - 1) & 3) * NLVL + lvl) * HDIM;
      u64 E0 = pollt(el + i0, (u32)(r + 1));
      u64 E1 = pollt(el + i1, (u32)(r + 1));
      u64 H0 = pollt(hold + i0, (u32)r);
      u64 H1 = pollt(hold + i1, (u32)r);
      u64 D = pollt(tg + TG_DPR + ((size_t)lvl * 4 + (r & 3)) * 8, (u32)(r + 1));
      float pr = sigmoid_f(tval(D));
      float e0 = tval(E0), e1 = tval(E1);
      xb[i0] = fmaf(pr, e0, tval(H0));
      xb[i1] = fmaf(pr, e1, tval(H1));
      if (threadIdx.x == 0 && r - lvl >= 4) {
        gscan<32>(progp(tg, lvl, 4), (u32)(r - 2));          // h ring (own reads)
        if (lvl < 3) gscan<8>(progp(tg, lvl + 1, 0), (u32)(r - 2)); // P1 above
      }
      __syncthreads();
      if (threadIdx.x == 0) pub(myprog, (u32)(r + 1));
      const float4* x4 = (const float4*)xb;
      float4 X0 = x4[lane], X1 = x4[lane + 64], X2 = x4[lane + 128], X3 = x4[lane + 192];
      float dk0 = 0.f, dk1 = 0.f, dk2 = 0.f;
#pragma unroll
      for (int k = 0; k < 12; ++k) {
        const int hr = k / 3, g = k % 3;
        float a;
        if constexpr (BF16) {
          a = bdot(Wr[k][0], X0, 0.f); a = bdot(Wr[k][1], X1, a);
          a = bdot(Wr[k][2], X2, a);  a = bdot(Wr[k][3], X3, a);
        } else {
          const int gsel = (g == 0) ? 0 : (g + 1);
          const float4* w =
              (const float4*)(Wih + ((size_t)gsel * HDIM + b4 + hr) * HDIM);
          float4 A0 = w[lane], A1 = w[lane + 64], A2 = w[lane + 128], A3 = w[lane + 192];
          a = dot4f(A0, X0, 0.f); a = dot4f(A1, X1, a);
          a = dot4f(A2, X2, a);   a = dot4f(A3, X3, a);
        }
        a = wredux_all(a);
        if (g == 0)      dk0 = (lane == hr) ? a : dk0;
        else if (g == 1) dk1 = (lane == hr) ? a : dk1;
        else             dk2 = (lane == hr) ? a : dk2;
      }
      if (lane < 4) {
        float gi = sigmoid_f(dk0 + mb0);
        float gg = tanhf(dk1 + mb1);
        float go = sigmoid_f(dk2 + mb2);
        tstore(hsT + (size_t)((r & 3) * NLVL + lvl) * HDIM + b4 + lane,
               go * tanhf(gi * gg), (u32)(r + 1));
      }
      if (wgl == 0) {   // fe += prec * sum(enc^2)
        float s = fmaf(e0, e0, e1 * e1);
        s = wredux_all(s);
        if (lane == 0) sred[wave] = s;
        __syncthreads();
        if (threadIdx.x == 0) {
          float tot = 0.f;
#pragma unroll
          for (int k = 0; k < NWAVES; ++k) tot += sred[k];
          fe_local += pr * tot;
        }
        __syncthreads();
      }
    }
    if (wgl == 0 && threadIdx.x == 0) {
      gstore((float*)(tg + TG_FE + (size_t)lvl * 8), fe_local);
      asm volatile("s_waitcnt vmcnt(0)" ::: "memory");
      __hip_atomic_fetch_add((u32*)(tg + TG_FIN), 1u, __ATOMIC_RELAXED,
                             __HIP_MEMORY_SCOPE_AGENT);
      if (lvl == 3) {
        int spin = 0;
        while (uload((u32*)(tg + TG_FIN)) < (u32)NLVL) {
          __builtin_amdgcn_s_sleep(1);
          if (++spin > SPIN_CAP) break;
        }
        float s = 0.f;
        for (int k = 0; k < NLVL; ++k)
          s += gload((float*)(tg + TG_FE + (size_t)k * 8));
        out[2 * NLVL * HDIM] = s;
      }
    }
  } else {
    // ================= square matvec phases =================
    const int wid = wgl * NWAVES + wave;        // 0..63
    const int base = wid * 16;
    uint2 Wr[16][4];
    const u16* Wb = nullptr; const float* Wf = nullptr;
    const float* bvec = nullptr;
    if (phase == 0)      { Wb = bw + BW_P1 + (size_t)lvl * HDIM * HDIM; Wf = pw1 + (size_t)lvl * HDIM * HDIM; bvec = pb1 + lvl * HDIM; }
    else if (phase == 1) { Wb = bw + BW_P2 + (size_t)lvl * HDIM * HDIM; Wf = pw2 + (size_t)lvl * HDIM * HDIM; bvec = pb2 + lvl * HDIM; }
    else if (phase == 2) { Wb = bw + BW_E1 + (size_t)lvl * HDIM * HDIM; Wf = ew1 + (size_t)lvl * HDIM * HDIM; bvec = eb1 + lvl * HDIM; }
    else                 { Wb = bw + BW_E2 + (size_t)lvl * HDIM * HDIM; Wf = ew2 + (size_t)lvl * HDIM * HDIM; bvec = eb2 + lvl * HDIM; }
    loadW16<BF16>(Wr, Wb, base, lane);
    float myb = (lane < 16) ? bvec[base + lane] : 0.f;

    u64* t1l = tg + TG_T1R + (size_t)lvl * 4 * HDIM;
    u64* erl = tg + TG_ERRR + (size_t)lvl * 4 * HDIM;
    u64* t2l = tg + TG_T2R + (size_t)lvl * 4 * HDIM;

    const bool doq = (phase == 2 && wgl == 0 && wave == 0);
    float4 Q0, Q1, Q2, Q3; float qbl = 0.f;
    if (doq) {
      const float4* q4 = (const float4*)(qw + lvl * HDIM);
      Q0 = q4[lane]; Q1 = q4[lane + 64]; Q2 = q4[lane + 128]; Q3 = q4[lane + 192];
      qbl = qb[lvl];
    }

    for (int r = lvl; r < lvl + SEQ; ++r) {
      const int t = r - lvl;
      float* xb = xl[r & 1];
      float my_e = 0.f;

      if (phase == 0) {
        fill_x(hsT + (size_t)(((r - 1) & 3) * NLVL + (lvl - 1)) * HDIM, nullptr,
               (u32)r, xb);
        if (threadIdx.x == 0 && t >= 4) gscan<8>(progp(tg, lvl, 1), (u32)(r - 3));
      } else if (phase == 1) {
        fill_x(t1l + (size_t)(r & 3) * HDIM, nullptr, (u32)(r + 1), xb);
        if (lane < 16)
          my_e = tval(pollt(encT + (size_t)(((r - 1) & 3) * NLVL + (lvl - 1)) * HDIM +
                                base + lane, (u32)r));
        if (threadIdx.x == 0 && t >= 4) gscan<8>(progp(tg, lvl, 2), (u32)(r - 3));
      } else if (phase == 2) {
        if (lvl == 0) fill_x(nullptr, observed + (size_t)t * HDIM, 0u, xb);
        else          fill_x(erl + (size_t)(r & 3) * HDIM, nullptr, (u32)(r + 1), xb);
        if (threadIdx.x == 0 && t >= 4) {
          gscan<8>(progp(tg, lvl, 3), (u32)(r - 3));
          gscan<32>(progp(tg, lvl, 4), (u32)(r - 3));
        }
      } else {
        fill_x(t2l + (size_t)(r & 3) * HDIM, nullptr, (u32)(r + 1), xb);
        if (threadIdx.x == 0 && t >= 4) {
          gscan<32>(progp(tg, lvl, 4), (u32)(r - 3));
          if (lvl < 3) gscan<8>(progp(tg, lvl + 1, 1), (u32)(r - 2));
        }
      }
      __syncthreads();
      if (threadIdx.x == 0) pub(myprog, (u32)(r + 1));

      float o = dot16_keep<BF16>(Wr, Wf, base, (const float4*)xb, lane);

      if (phase == 0) {
        if (lane < 16)
          tstore(t1l + (size_t)(r & 3) * HDIM + base + lane, gelu_f(o + myb),
                 (u32)(r + 1));
      } else if (phase == 1) {
        if (lane < 16) {
          float p = o + myb;
          tstore(erl + (size_t)(r & 3) * HDIM + base + lane, my_e - p, (u32)(r + 1));
          if (t == SEQ - 1) out[lvl * HDIM + base + lane] = p;
        }
      } else if (phase == 2) {
        if (lane < 16)
          tstore(t2l + (size_t)(r & 3) * HDIM + base + lane, gelu_f(o + myb),
                 (u32)(r + 1));
        if (doq) {
          const float4* x4 = (const float4*)xb;
          float d = dot4f(Q0, x4[lane], 0.f);
          d = dot4f(Q1, x4[lane + 64], d);
          d = dot4f(Q2, x4[lane + 128], d);
          d = dot4f(Q3, x4[lane + 192], d);
          d = wredux_all(d);
          if (lane == 0)
            tstore(tg + TG_DPR + ((size_t)lvl * 4 + (r & 3)) * 8, d + qbl,
                   (u32)(r + 1));
        }
        if (lvl == 0 && t == SEQ - 1) {
          int i = wgl * THREADS + threadIdx.x;
          if (i < HDIM) out[i] = 0.f;
        }
      } else {
        if (lane < 16) {
          float e = o + myb;
          tstore(encT + (size_t)((r & 3) * NLVL + lvl) * HDIM + base + lane, e,
                 (u32)(r + 1));
          if (t == SEQ - 1) out[NLVL * HDIM + lvl * HDIM + base + lane] = e;
        }
      }
    }
  }
}

extern "C" void kernel_launch(void* const* d_in, const int* in_sizes, int n_in,
                              void* d_out, int out_size, void* d_ws, size_t ws_size,
                              hipStream_t stream) {
  const float* observed = (const float*)d_in[0];
  const float* pw1 = (const float*)d_in[1];
  const float* pb1 = (const float*)d_in[2];
  const float* pw2 = (const float*)d_in[3];
  const float* pb2 = (const float*)d_in[4];
  const float* ew1 = (const float*)d_in[5];
  const float* eb1 = (const float*)d_in[6];
  const float* ew2 = (const float*)d_in[7];
  const float* eb2 = (const float*)d_in[8];
  const float* qw  = (const float*)d_in[9];
  const float* qb  = (const float*)d_in[10];
  const float* wih = (const float*)d_in[11];
  // d_in[12] = whh — unused (h0 == 0 per step)
  const float* bih = (const float*)d_in[13];
  const float* bhh = (const float*)d_in[14];
  float* out = (float*)d_out;
  u64* tg = (u64*)d_ws;
  u16* bw = (u16*)((char*)d_ws + (size_t)TG_END * 8);

  const size_t need = (size_t)TG_END * 8 + (size_t)BW_TOTAL * 2;
  const bool use_bf16 = (ws_size >= need);

  hipLaunchKernelGGL(tpn_init, dim3(64), dim3(256), 0, stream, tg);

  if (use_bf16) {
    const int nsq = NLVL * HDIM * HDIM;
    hipLaunchKernelGGL(cvt_sq, dim3(512), dim3(256), 0, stream, pw1, bw + BW_P1, nsq);
    hipLaunchKernelGGL(cvt_sq, dim3(512), dim3(256), 0, stream, pw2, bw + BW_P2, nsq);
    hipLaunchKernelGGL(cvt_sq, dim3(512), dim3(256), 0, stream, ew1, bw + BW_E1, nsq);
    hipLaunchKernelGGL(cvt_sq, dim3(512), dim3(256), 0, stream, ew2, bw + BW_E2, nsq);
    hipLaunchKernelGGL(cvt_ih, dim3(512), dim3(256), 0, stream, wih, bw + BW_IH);
  }

  const u16* bwc = bw;
  void* args[] = { &observed, &pw1, &pb1, &pw2, &pb2, &ew1, &eb1, &ew2, &eb2,
                   &qw, &qb, &wih, &bih, &bhh, &out, &tg, &bwc };
  if (use_bf16) {
    (void)hipLaunchCooperativeKernel((void*)tpn_main_t<true>, dim3(NWG),
                                     dim3(THREADS), args, 0, stream);
  } else {
    (void)hipLaunchCooperativeKernel((void*)tpn_main_t<false>, dim3(NWG),
                                     dim3(THREADS), args, 0, stream);
  }
}